// Round 7
// baseline (1057.930 us; speedup 1.0000x reference)
//
#include <hip/hip_runtime.h>

#define HH   64
#define BPTS 256          // points per block/chunk
#define LPB  4096         // points per batch
#define NBAT 256
#define NPTS (NBAT * LPB) // 1,048,576 points

typedef _Float16 f16x8 __attribute__((ext_vector_type(8)));
typedef float    f32x4 __attribute__((ext_vector_type(4)));

// ---------- swizzled addressing for a [R][64] f16 plane (16B-block XOR)
// logical (r,c) -> element offset; block m = c>>3 stored at m ^ (r&7)
__device__ __forceinline__ int fofs(int r, int c) {
    return (r << 6) | ((((c >> 3) ^ (r & 7))) << 3) | (c & 7);
}
__device__ __forceinline__ int bofs(int r, int m) {
    return (r << 6) | ((m ^ (r & 7)) << 3);
}
__device__ __forceinline__ f16x8 rd8(const _Float16* p, int r, int m) {
    return *(const f16x8*)&p[bofs(r, m)];
}

// ---------- split-f16: v ~= hi + lo, |v-(hi+lo)| <= 2^-22 |v|
__device__ __forceinline__ void split2(float v, _Float16& h, _Float16& l) {
    h = (_Float16)v;
    l = (_Float16)(v - (float)h);
}

// ---------- 32x64x64 GEMM tile per wave via MFMA, 3-term split-f16.
// A rows rb..rb+31 from (ah_,al_), B cols from (wh_,wl_); fp32 accum.
__device__ __forceinline__ void mfma_gemm(const _Float16* ah_, const _Float16* al_,
                                          const _Float16* wh_, const _Float16* wl_,
                                          int rb, int lane, f32x4 acc[2][4]) {
    const int rA = rb + (lane & 15);
    const int cB = lane & 15;
    const int g  = lane >> 4;
#pragma unroll
    for (int s = 0; s < 2; ++s) {
        const int m = s * 4 + g;        // k-block: k = 8m..8m+7
        f16x8 Ah[2], Al[2];
#pragma unroll
        for (int rt = 0; rt < 2; ++rt) {
            Ah[rt] = rd8(ah_, rA + 16 * rt, m);
            Al[rt] = rd8(al_, rA + 16 * rt, m);
        }
#pragma unroll
        for (int ct = 0; ct < 4; ++ct) {
            f16x8 Bh = rd8(wh_, cB + 16 * ct, m);
            f16x8 Bl = rd8(wl_, cB + 16 * ct, m);
#pragma unroll
            for (int rt = 0; rt < 2; ++rt) {
                acc[rt][ct] = __builtin_amdgcn_mfma_f32_16x16x32_f16(Ah[rt], Bh, acc[rt][ct], 0, 0, 0);
                acc[rt][ct] = __builtin_amdgcn_mfma_f32_16x16x32_f16(Ah[rt], Bl, acc[rt][ct], 0, 0, 0);
                acc[rt][ct] = __builtin_amdgcn_mfma_f32_16x16x32_f16(Al[rt], Bh, acc[rt][ct], 0, 0, 0);
            }
        }
    }
}

// ---------- write activations (C/D layout: row=rb+16rt+4g+reg, col=16ct+(lane&15))
__device__ __forceinline__ void write_acts(_Float16* hi, _Float16* lo,
                                           const f32x4 t[2][4], int rb, int lane) {
    const int g = lane >> 4, cb = lane & 15;
#pragma unroll
    for (int rt = 0; rt < 2; ++rt)
#pragma unroll
        for (int reg = 0; reg < 4; ++reg) {
            const int r = rb + 16 * rt + 4 * g + reg;
#pragma unroll
            for (int ct = 0; ct < 4; ++ct) {
                _Float16 h, l;
                split2(t[rt][ct][reg], h, l);
                const int o = fofs(r, 16 * ct + cb);
                hi[o] = h; lo[o] = l;
            }
        }
}

// ---------- stage 64x64 fp32 weight tile -> hi/lo planes (512 threads, 8 w/thread)
__device__ __forceinline__ void stage_w(_Float16* wh, _Float16* wl,
                                        const float* __restrict__ W, int tid, int ldw) {
    const int o = tid >> 3, k0 = (tid & 7) << 3;
    const float* wr = &W[(size_t)o * ldw + k0];
    float4 a = *(const float4*)wr;
    float4 b = *(const float4*)(wr + 4);
    float v[8] = {a.x, a.y, a.z, a.w, b.x, b.y, b.z, b.w};
    f16x8 h, l;
#pragma unroll
    for (int i = 0; i < 8; ++i) { _Float16 hh, ll; split2(v[i], hh, ll); h[i] = hh; l[i] = ll; }
    const int ofs = bofs(o, k0 >> 3);
    *(f16x8*)&wh[ofs] = h;
    *(f16x8*)&wl[ofs] = l;
}

// ---------- order-preserving float<->uint encoding (atomicMax on signed floats)
__device__ __forceinline__ unsigned encf(float f) {
    unsigned u = __float_as_uint(f);
    return (u & 0x80000000u) ? ~u : (u | 0x80000000u);
}
__device__ __forceinline__ float decf(unsigned u) {
    return (u & 0x80000000u) ? __uint_as_float(u ^ 0x80000000u) : __uint_as_float(~u);
}

__global__ __launch_bounds__(256) void k_init(float* gbuf, unsigned* oenc) {
    int i = blockIdx.x * 256 + threadIdx.x;
    if (i < 4 * NBAT * HH) gbuf[i] = 0.0f;
    if (i < NBAT * HH)     oenc[i] = 0x007FFFFFu; // encf(-inf)
}

// ---------- per-(li,batch) goff: goff[b][o] = gb[li][o] + sum_k g[b][k]*gw[li][o][64+k]
__global__ __launch_bounds__(64) void k_goff(const float* __restrict__ g,
                                             const float* __restrict__ gw,
                                             const float* __restrict__ gb,
                                             float* __restrict__ goff, int li) {
    const int b = blockIdx.x, o = threadIdx.x;
    const float* gr = &g[b * HH];
    const float* wr = &gw[(size_t)li * 64 * 128 + o * 128 + 64];
    float s = gb[li * 64 + o];
#pragma unroll
    for (int k = 0; k < 64; k += 4) {
        float4 w4 = *(const float4*)&wr[k];
        float4 g4 = *(const float4*)&gr[k];
        s = fmaf(g4.x, w4.x, fmaf(g4.y, w4.y, fmaf(g4.z, w4.z, fmaf(g4.w, w4.w, s))));
    }
    goff[(size_t)b * HH + o] = s;
}

// ---------- fused forward (recompute ladder; tiny ws, crash-safe). 512 threads, 8 waves.
template<int NSTAGE, bool DO_OUT>
__global__ __launch_bounds__(512, 4) void k_fused(
    const float* __restrict__ x, const float* __restrict__ piw,
    const float* __restrict__ pib, const float* __restrict__ lyrw,
    const float* __restrict__ lyrb, const float* __restrict__ gw,
    const float* __restrict__ pw, const float* __restrict__ pob,
    const float* __restrict__ goffb, float* __restrict__ gmax,
    unsigned* __restrict__ oenc) {
    __shared__ __align__(16) _Float16 a_hi[BPTS * HH]; // 32 KB
    __shared__ __align__(16) _Float16 a_lo[BPTS * HH]; // 32 KB
    __shared__ __align__(16) _Float16 w_hi[HH * HH];   // 8 KB
    __shared__ __align__(16) _Float16 w_lo[HH * HH];   // 8 KB
    const int tid  = threadIdx.x;
    const int lane = tid & 63, wave = tid >> 6;
    const int rb   = wave << 5;           // this wave's 32 point-rows
    const int pbase = blockIdx.x * BPTS;
    const int b = pbase / LPB;
    int ch4[4];
#pragma unroll
    for (int ct = 0; ct < 4; ++ct) ch4[ct] = 16 * ct + (lane & 15);

    // ---- prologue: proj_in (2 threads per point, 32 ch each) + lyr0 weights
    stage_w(w_hi, w_lo, lyrw, tid, 64);
    {
        const int p = tid >> 1, half = tid & 1;
        const size_t pidx = (size_t)(pbase + p) * 3;
        const float x0 = x[pidx], x1 = x[pidx + 1], x2 = x[pidx + 2];
#pragma unroll
        for (int j = 0; j < 4; ++j) {
            const int o0 = half * 32 + j * 8;
            f16x8 h, l;
#pragma unroll
            for (int i = 0; i < 8; ++i) {
                const int o = o0 + i;
                float v = fmaxf(fmaf(piw[o * 3], x0,
                              fmaf(piw[o * 3 + 1], x1,
                              fmaf(piw[o * 3 + 2], x2, pib[o]))), 0.0f);
                _Float16 hh, ll; split2(v, hh, ll);
                h[i] = hh; l[i] = ll;
            }
            const int ofs = bofs(p, o0 >> 3);
            *(f16x8*)&a_hi[ofs] = h;
            *(f16x8*)&a_lo[ofs] = l;
        }
    }
    __syncthreads();

    f32x4 acc[2][4];
#pragma unroll
    for (int rt = 0; rt < 2; ++rt)
#pragma unroll
        for (int ct = 0; ct < 4; ++ct) {
            const float bb = lyrb[ch4[ct]];
            acc[rt][ct] = (f32x4){bb, bb, bb, bb};
        }
    mfma_gemm(a_hi, a_lo, w_hi, w_lo, rb, lane, acc);  // acc = pre-relu a_0

    f32x4 oacc[2][4];
    if (DO_OUT) {
#pragma unroll
        for (int rt = 0; rt < 2; ++rt)
#pragma unroll
            for (int ct = 0; ct < 4; ++ct) oacc[rt][ct] = (f32x4){0.f, 0.f, 0.f, 0.f};
    }

    constexpr int NITER = DO_OUT ? 4 : (NSTAGE - 1);
#pragma unroll
    for (int li = 0; li < NITER; ++li) {
#pragma unroll
        for (int rt = 0; rt < 2; ++rt)
#pragma unroll
            for (int ct = 0; ct < 4; ++ct)
#pragma unroll
                for (int r = 0; r < 4; ++r)
                    acc[rt][ct][r] = fmaxf(acc[rt][ct][r], 0.0f);   // a_li

        __syncthreads();                       // prev gemm reads done
        write_acts(a_hi, a_lo, acc, rb, lane); // a_lds = a_li
        stage_w(w_hi, w_lo, &gw[(size_t)li * 64 * 128], tid, 128);
        __syncthreads();

        f32x4 a2[2][4];
#pragma unroll
        for (int rt = 0; rt < 2; ++rt)
#pragma unroll
            for (int ct = 0; ct < 4; ++ct) {
                const float gv = goffb[(size_t)li * NBAT * HH + (size_t)b * HH + ch4[ct]];
                a2[rt][ct] = (f32x4){gv, gv, gv, gv};
            }
        mfma_gemm(a_hi, a_lo, w_hi, w_lo, rb, lane, a2);
#pragma unroll
        for (int rt = 0; rt < 2; ++rt)
#pragma unroll
            for (int ct = 0; ct < 4; ++ct)
#pragma unroll
                for (int r = 0; r < 4; ++r)
                    a2[rt][ct][r] = fmaxf(a2[rt][ct][r], 0.0f);     // x_li

        __syncthreads();                       // glyr gemm reads done
        write_acts(a_hi, a_lo, a2, rb, lane);  // a_lds = x_li
        if (DO_OUT) {
            stage_w(w_hi, w_lo, &pw[(size_t)li * 64], tid, 256);
            __syncthreads();
            mfma_gemm(a_hi, a_lo, w_hi, w_lo, rb, lane, oacc);  // out partial +=
            if (li < 3) {
                __syncthreads();
                stage_w(w_hi, w_lo, &lyrw[(size_t)(li + 1) * 4096], tid, 64);
                __syncthreads();
            }
        } else {
            stage_w(w_hi, w_lo, &lyrw[(size_t)(li + 1) * 4096], tid, 64);
            __syncthreads();
        }
        if (li < 3) {
#pragma unroll
            for (int rt = 0; rt < 2; ++rt)
#pragma unroll
                for (int ct = 0; ct < 4; ++ct) {
                    const float bb = lyrb[(li + 1) * 64 + ch4[ct]];
                    acc[rt][ct] = (f32x4){bb, bb, bb, bb};
                }
            mfma_gemm(a_hi, a_lo, w_hi, w_lo, rb, lane, acc);   // pre-relu a_{li+1}
        }
    }

    // ---- epilogue: per-wave channel max, cross-wave reduce (reuse a_hi), atomics
    float m4[4];
    if (!DO_OUT) {
#pragma unroll
        for (int ct = 0; ct < 4; ++ct) m4[ct] = 0.0f;
#pragma unroll
        for (int rt = 0; rt < 2; ++rt)
#pragma unroll
            for (int ct = 0; ct < 4; ++ct)
#pragma unroll
                for (int r = 0; r < 4; ++r)
                    m4[ct] = fmaxf(m4[ct], fmaxf(acc[rt][ct][r], 0.0f));
    } else {
#pragma unroll
        for (int ct = 0; ct < 4; ++ct) m4[ct] = -3.4e38f;
#pragma unroll
        for (int rt = 0; rt < 2; ++rt)
#pragma unroll
            for (int ct = 0; ct < 4; ++ct)
#pragma unroll
                for (int r = 0; r < 4; ++r)
                    m4[ct] = fmaxf(m4[ct], oacc[rt][ct][r]);
    }
#pragma unroll
    for (int ct = 0; ct < 4; ++ct) {
        m4[ct] = fmaxf(m4[ct], __shfl_xor(m4[ct], 16, 64));
        m4[ct] = fmaxf(m4[ct], __shfl_xor(m4[ct], 32, 64));
    }
    __syncthreads();                        // all gemm reads of a_lds done
    float* red = (float*)a_hi;              // reuse as 8x64 f32 reduce buffer
    if ((lane >> 4) == 0)
#pragma unroll
        for (int ct = 0; ct < 4; ++ct)
            red[wave * 64 + ct * 16 + (lane & 15)] = m4[ct];
    __syncthreads();
    if (tid < 64) {
        float v = red[tid];
#pragma unroll
        for (int w = 1; w < 8; ++w) v = fmaxf(v, red[w * 64 + tid]);
        if (!DO_OUT)
            atomicMax((unsigned*)&gmax[b * HH + tid], __float_as_uint(v));
        else
            atomicMax(&oenc[b * HH + tid], encf(v + pob[tid]));
    }
}

__global__ __launch_bounds__(256) void k_dec(const unsigned* __restrict__ oenc,
                                             float* __restrict__ out) {
    int i = blockIdx.x * 256 + threadIdx.x;
    out[i] = decf(oenc[i]);
}

extern "C" void kernel_launch(void* const* d_in, const int* in_sizes, int n_in,
                              void* d_out, int out_size, void* d_ws, size_t ws_size,
                              hipStream_t stream) {
    const float* x    = (const float*)d_in[0];
    const float* piw  = (const float*)d_in[1];
    const float* pib  = (const float*)d_in[2];
    const float* lyrw = (const float*)d_in[3];
    const float* lyrb = (const float*)d_in[4];
    const float* gw   = (const float*)d_in[5];
    const float* gb   = (const float*)d_in[6];
    const float* pw   = (const float*)d_in[7];
    const float* pob  = (const float*)d_in[8];
    float* out = (float*)d_out;

    // ws layout (tiny, ~0.6 MB): g[4][256][64] f32 | oenc[256*64] u32 | goff[4][256][64] f32
    float* gbuf    = (float*)d_ws;
    unsigned* oenc = (unsigned*)(gbuf + 4 * NBAT * HH);
    float* goffbuf = (float*)(oenc + NBAT * HH);

    const int nblk = NPTS / BPTS; // 4096

    k_init<<<256, 256, 0, stream>>>(gbuf, oenc);

    k_fused<1, false><<<nblk, 512, 0, stream>>>(x, piw, pib, lyrw, lyrb, gw, pw, pob,
                                                goffbuf, gbuf, oenc);
    k_goff<<<NBAT, 64, 0, stream>>>(gbuf, gw, gb, goffbuf, 0);

    k_fused<2, false><<<nblk, 512, 0, stream>>>(x, piw, pib, lyrw, lyrb, gw, pw, pob,
                                                goffbuf, gbuf + NBAT * HH, oenc);
    k_goff<<<NBAT, 64, 0, stream>>>(gbuf + NBAT * HH, gw, gb, goffbuf + NBAT * HH, 1);

    k_fused<3, false><<<nblk, 512, 0, stream>>>(x, piw, pib, lyrw, lyrb, gw, pw, pob,
                                                goffbuf, gbuf + 2 * NBAT * HH, oenc);
    k_goff<<<NBAT, 64, 0, stream>>>(gbuf + 2 * NBAT * HH, gw, gb, goffbuf + 2 * NBAT * HH, 2);

    k_fused<4, false><<<nblk, 512, 0, stream>>>(x, piw, pib, lyrw, lyrb, gw, pw, pob,
                                                goffbuf, gbuf + 3 * NBAT * HH, oenc);
    k_goff<<<NBAT, 64, 0, stream>>>(gbuf + 3 * NBAT * HH, gw, gb, goffbuf + 3 * NBAT * HH, 3);

    k_fused<4, true><<<nblk, 512, 0, stream>>>(x, piw, pib, lyrw, lyrb, gw, pw, pob,
                                               goffbuf, nullptr, oenc);

    k_dec<<<(NBAT * HH) / 256, 256, 0, stream>>>(oenc, out);
}